// Round 3
// baseline (356.541 us; speedup 1.0000x reference)
//
#include <hip/hip_runtime.h>
#include <hip/hip_bf16.h>

// Problem constants
#define IN_C   64
#define OUT_D  47          // (24-1)*2 - 2*1 + 3
#define XD     24
#define XSP    (XD*XD*XD)  // 13824
#define OSP    (OUT_D*OUT_D*OUT_D) // 103823
#define BATCH  16

#define NSPLIT 4
#define CPG    (IN_C / NSPLIT)   // 16 channels per block

// LDS halo tile: 10 z-planes x 10 y-rows x 28 floats (idx 0 <-> gx=-1 pad,
// idx 25 <-> gx=24 pad, idx 26..27 stride pad; pads stay zero forever).
#define LROW   28
#define LDS_N  (10 * 10 * LROW)   // 2800 floats = 11.2 KB

// Effective weights, laid out for the compute loop:
//   weff[c*64 + (pd*2+dd)*16 + (((ph*2+pw)*2+dh)*2+dw)]
// Per dim: S(p=0,d=0)={2}, S(0,1)={0,1}, S(1,0)={1,2}, S(1,1)={0}
__global__ void weff_prep(const float* __restrict__ w, float* __restrict__ weff) {
    int c = threadIdx.x;   // 64 threads
    float wv[27];
    const float* wc = w + (size_t)c * 64 * 27;   // weight[c][0][*]
    #pragma unroll
    for (int z = 0; z < 27; z++) wv[z] = wc[z];
    const int msk[2][2] = {{4, 3}, {6, 1}};       // bit z set iff z in S(p,delta)
    #pragma unroll
    for (int pd = 0; pd < 2; pd++)
    #pragma unroll
    for (int dd = 0; dd < 2; dd++)
    #pragma unroll
    for (int ph = 0; ph < 2; ph++)
    #pragma unroll
    for (int pw = 0; pw < 2; pw++)
    #pragma unroll
    for (int dh = 0; dh < 2; dh++)
    #pragma unroll
    for (int dw = 0; dw < 2; dw++) {
        float s = 0.f;
        for (int zd = 0; zd < 3; zd++) if ((msk[pd][dd] >> zd) & 1)
            for (int zh = 0; zh < 3; zh++) if ((msk[ph][dh] >> zh) & 1)
                for (int zw = 0; zw < 3; zw++) if ((msk[pw][dw] >> zw) & 1)
                    s += wv[zd * 9 + zh * 3 + zw];
        weff[c * 64 + (pd * 2 + dd) * 16 + (((ph * 2 + pw) * 2 + dh) * 2 + dw)] = s;
    }
}

// Main kernel. Block m-tile: 8 (d) x 8 (h) x 24 (w, full). 192 threads:
// (td,th,tw) = (tid/24, (tid/6)%4, tid%6). Per-thread m-region:
// md = Bd+td (1), mh = Bh+2*th+{0,1} (2), mw = 4*tw+{0..3} (4) -> 8 m-voxels,
// 64 outputs (x8 parities), 64 accs, 512 FMA per channel.
__global__ __launch_bounds__(192) void tconv(const float* __restrict__ x,
                                             const float* __restrict__ weff,
                                             const float* __restrict__ bias,
                                             float* __restrict__ out) {
    __shared__ float xs[LDS_N];
    const int b = blockIdx.x;           // ((sp*NSPLIT + g)*16 + n), n fastest
    const int n = b & 15;
    const int r1 = b >> 4;
    const int g = r1 & (NSPLIT - 1);
    const int sp = r1 >> 2;             // 0..8
    const int tzi = sp / 3;
    const int tyi = sp - tzi * 3;
    const int Bd = tzi * 8, Bh = tyi * 8;

    const int tid = threadIdx.x;
    const int tw = tid % 6;
    const int th = (tid / 6) % 4;
    const int td = tid / 24;            // 0..7

    // ---- zero-fill LDS once (pads + OOB rows stay zero forever) ----
    for (int i = tid; i < LDS_N; i += 192) xs[i] = 0.f;

    // ---- staging descriptors: 600 float4-rows-of-24 per channel ----
    int  goff[4], lbase[4];
    bool vld[4];
    #pragma unroll
    for (int k = 0; k < 4; k++) {
        int f = tid + 192 * k;          // float4 index, 0..767 (600 used)
        int r = f / 6, q = f - 6 * r;   // r = halo row (z*10+y), q = quad in row
        int gz = Bd - 1 + r / 10;
        int gy = Bh - 1 + (r - (r / 10) * 10);
        vld[k] = (f < 600) && ((unsigned)gz < (unsigned)XD) &&
                 ((unsigned)gy < (unsigned)XD);
        goff[k] = vld[k] ? ((gz * XD + gy) * XD + 4 * q) : 0;
        lbase[k] = r * LROW + 1 + 4 * q;
    }

    const float* xg = x + (size_t)n * IN_C * XSP + (size_t)g * CPG * XSP;

    // prologue prefetch: channel 0
    float4 pre[4];
    #pragma unroll
    for (int k = 0; k < 4; k++)
        pre[k] = vld[k] ? *(const float4*)(xg + goff[k])
                        : make_float4(0.f, 0.f, 0.f, 0.f);

    float acc[2][2][2][2][4];           // [pd][ph][pw][b][j]
    #pragma unroll
    for (int i0 = 0; i0 < 2; i0++)
    #pragma unroll
    for (int i1 = 0; i1 < 2; i1++)
    #pragma unroll
    for (int i2 = 0; i2 < 2; i2++)
    #pragma unroll
    for (int i3 = 0; i3 < 2; i3++)
    #pragma unroll
    for (int i4 = 0; i4 < 4; i4++) acc[i0][i1][i2][i3][i4] = 0.f;

    #pragma unroll 1
    for (int cc = 0; cc < CPG; cc++) {
        __syncthreads();                 // prev compute (or zero-fill) done
        #pragma unroll
        for (int k = 0; k < 4; k++) {
            if (vld[k]) {
                xs[lbase[k] + 0] = pre[k].x;
                xs[lbase[k] + 1] = pre[k].y;
                xs[lbase[k] + 2] = pre[k].z;
                xs[lbase[k] + 3] = pre[k].w;
            }
        }
        __syncthreads();

        // prefetch next channel during compute
        if (cc + 1 < CPG) {
            const float* xc2 = xg + (size_t)(cc + 1) * XSP;
            #pragma unroll
            for (int k = 0; k < 4; k++)
                if (vld[k]) pre[k] = *(const float4*)(xc2 + goff[k]);
        }

        const float* Wc = weff + (size_t)(g * CPG + cc) * 64;  // uniform -> s_load

        #pragma unroll
        for (int zo = 0; zo < 3; zo++) {
            // load this z-plane's 4x6 strip: b128 + b64 (both aligned)
            float xvp[4][6];
            #pragma unroll
            for (int dy = 0; dy < 4; dy++) {
                int base = ((td + zo) * 10 + th * 2 + dy) * LROW + 4 * tw;
                float4 t0 = *(const float4*)&xs[base];
                float2 t1 = *(const float2*)&xs[base + 4];
                xvp[dy][0] = t0.x; xvp[dy][1] = t0.y;
                xvp[dy][2] = t0.z; xvp[dy][3] = t0.w;
                xvp[dy][4] = t1.x; xvp[dy][5] = t1.y;
            }
            #pragma unroll
            for (int pd = 0; pd < 2; pd++)
            #pragma unroll
            for (int dd = 0; dd < 2; dd++) {
                if (pd + dd != zo) continue;
                const float* Wg = Wc + (pd * 2 + dd) * 16;
                #pragma unroll
                for (int ph = 0; ph < 2; ph++)
                #pragma unroll
                for (int pw = 0; pw < 2; pw++)
                #pragma unroll
                for (int dh = 0; dh < 2; dh++)
                #pragma unroll
                for (int dw = 0; dw < 2; dw++) {
                    const float wgt = Wg[((ph * 2 + pw) * 2 + dh) * 2 + dw];
                    #pragma unroll
                    for (int bb = 0; bb < 2; bb++)
                    #pragma unroll
                    for (int j = 0; j < 4; j++)
                        acc[pd][ph][pw][bb][j] +=
                            wgt * xvp[bb + ph + dh][j + pw + dw];
                }
            }
        }
    }

    // ---- epilogue: atomic partials ----
    const float bpart = bias[0] * (64.0f / NSPLIT);
    float* on = out + (size_t)n * OSP;
    #pragma unroll
    for (int pd = 0; pd < 2; pd++)
    #pragma unroll
    for (int ph = 0; ph < 2; ph++)
    #pragma unroll
    for (int pw = 0; pw < 2; pw++)
    #pragma unroll
    for (int bb = 0; bb < 2; bb++)
    #pragma unroll
    for (int j = 0; j < 4; j++) {
        int od = 2 * (Bd + td) + pd;
        int oh = 2 * (Bh + 2 * th + bb) + ph;
        int ow = 2 * (4 * tw + j) + pw;
        if (od < OUT_D && oh < OUT_D && ow < OUT_D)
            atomicAdd(&on[(od * OUT_D + oh) * OUT_D + ow],
                      acc[pd][ph][pw][bb][j] * 64.0f + bpart);
    }
}

extern "C" void kernel_launch(void* const* d_in, const int* in_sizes, int n_in,
                              void* d_out, int out_size, void* d_ws, size_t ws_size,
                              hipStream_t stream) {
    const float* x      = (const float*)d_in[0];
    const float* weight = (const float*)d_in[1];
    const float* bias   = (const float*)d_in[2];
    float* out = (float*)d_out;
    float* weff = (float*)d_ws;        // 64*64 floats = 16 KB

    hipMemsetAsync(out, 0, (size_t)out_size * sizeof(float), stream);
    hipLaunchKernelGGL(weff_prep, dim3(1), dim3(64), 0, stream, weight, weff);

    dim3 grid(9 * NSPLIT * BATCH, 1, 1);   // 576 blocks, n fastest
    hipLaunchKernelGGL(tconv, grid, dim3(192), 0, stream, x, weff, bias, out);
}

// Round 4
// 160.741 us; speedup vs baseline: 2.2181x; 2.2181x over previous
//
#include <hip/hip_runtime.h>

// Problem constants
#define IN_C   64
#define OUT_D  47          // (24-1)*2 - 2*1 + 3
#define XD     24
#define XSP    (XD*XD*XD)  // 13824
#define OSP    (OUT_D*OUT_D*OUT_D) // 103823
#define BATCH  16

// LDS geometry: per-wave halo buffer, 100 rows (10z x 10y) x 24-float stride.
// Row content floats 0..15 = [orig 3..10 | orig 7..14] (orig i <-> gx = Bw-4+i),
// i.e. content quads u0=gx[Bw-1..Bw+2], u1=u2=gx[Bw+3..Bw+6], u3=gx[Bw+7..Bw+10],
// each quad stored at float offset 4*(u ^ ((row>>1)&3))  (bank swizzle).
#define RS     24
#define NROWS  100
#define WBUF   (NROWS*RS)   // 2400 floats = 9.6 KB per wave

typedef float f4u __attribute__((ext_vector_type(4), aligned(4)));

// Effective weights: weff[c*64 + (pd*2+dd)*16 + (((ph*2+pw)*2+dh)*2+dw)]
// Per dim: S(p=0,d=0)={2}, S(0,1)={0,1}, S(1,0)={1,2}, S(1,1)={0}
__global__ void weff_prep(const float* __restrict__ w, float* __restrict__ weff) {
    int c = threadIdx.x;   // 64 threads
    float wv[27];
    const float* wc = w + (size_t)c * 64 * 27;   // weight[c][0][*]
    #pragma unroll
    for (int z = 0; z < 27; z++) wv[z] = wc[z];
    const int msk[2][2] = {{4, 3}, {6, 1}};
    #pragma unroll
    for (int pd = 0; pd < 2; pd++)
    #pragma unroll
    for (int dd = 0; dd < 2; dd++)
    #pragma unroll
    for (int ph = 0; ph < 2; ph++)
    #pragma unroll
    for (int pw = 0; pw < 2; pw++)
    #pragma unroll
    for (int dh = 0; dh < 2; dh++)
    #pragma unroll
    for (int dw = 0; dw < 2; dw++) {
        float s = 0.f;
        for (int zd = 0; zd < 3; zd++) if ((msk[pd][dd] >> zd) & 1)
            for (int zh = 0; zh < 3; zh++) if ((msk[ph][dh] >> zh) & 1)
                for (int zw = 0; zw < 3; zw++) if ((msk[pw][dw] >> zw) & 1)
                    s += wv[zd * 9 + zh * 3 + zw];
        weff[c * 64 + (pd * 2 + dd) * 16 + (((ph * 2 + pw) * 2 + dh) * 2 + dw)] = s;
    }
}

// 432 blocks (27 sp-tiles x 16 n, n in low bits -> XCD = n%8), 256 threads.
// Wave wv handles channels [16*wv, 16*wv+16) over the block's 8x8x8 m-tile;
// lane: tw = L&1 (4 m-w each), th = (L>>1)&3 (2 m-h each), td = L>>3 (1 m-d).
// 64 fp32 accs/thread; in-block LDS tree-reduce; plain coalesced-ish stores.
__global__ __launch_bounds__(256) void tconv(const float* __restrict__ x,
                                             const float* __restrict__ weff,
                                             const float* __restrict__ bias,
                                             float* __restrict__ out) {
    __shared__ float xs[4 * WBUF];   // 9600 floats = 38.4 KB
    const int b = blockIdx.x;
    const int n = b & 15;
    const int sp = b >> 4;           // 0..26
    const int tz = sp / 9;
    const int r9 = sp - tz * 9;
    const int ty = r9 / 3;
    const int tx = r9 - ty * 3;
    const int Bd = tz * 8, Bh = ty * 8, Bw = tx * 8;

    const int tid = threadIdx.x;
    const int wv = tid >> 6;         // wave 0..3
    const int L  = tid & 63;
    const int tw = L & 1;
    const int th = (L >> 1) & 3;
    const int td = L >> 3;

    float* ws = xs + wv * WBUF;

    // one-time zero fill: halo cells (never re-written) must read as 0
    for (int i = tid; i < 4 * WBUF; i += 256) xs[i] = 0.f;
    __syncthreads();

    // ---- channel-invariant staging descriptors: 5 units/lane, e = k*64+L ----
    // unit = (row, s): s=0 -> gx Bw-1 (quad u0), s=1 -> gx Bw+3 (u1,u2), s=2 -> gx Bw+7 (u3)
    int  goffs[5], laddr[5], laddr2[5], etype[5];  // etype: -1 inval, 0 full, 1 shiftL, 2 scalarR
    #pragma unroll
    for (int k = 0; k < 5; k++) {
        int e = k * 64 + L;
        int row = e / 3;
        int s = e - 3 * row;
        int z = row / 10;
        int y = row - z * 10;
        int gz = Bd - 1 + z, gy = Bh - 1 + y;
        bool rowv = (e < 300) && ((unsigned)gz < (unsigned)XD) && ((unsigned)gy < (unsigned)XD);
        int gxs = Bw + 4 * s - 1;            // {Bw-1, Bw+3, Bw+7}
        int et;
        if (!rowv) et = -1;
        else if (gxs < 0) et = 1;            // only s=0, Bw=0
        else if (gxs + 3 > 23) et = 2;       // only s=2, Bw=16 (gxs=23)
        else et = 0;
        etype[k] = et;
        int gld = gxs < 0 ? 0 : gxs;
        goffs[k] = (gz * XD + gy) * XD + gld;
        int sg = (row >> 1) & 3;
        int upri = (s == 0) ? 0 : (s == 1 ? 1 : 3);
        laddr[k]  = row * RS + 4 * (upri ^ sg);
        laddr2[k] = (s == 1) ? (row * RS + 4 * (2 ^ sg)) : -1;
    }

    const float* xg = x + ((size_t)n * IN_C + wv * 16) * XSP;

    // ---- prologue prefetch: channel 0 ----
    float4 pre[5];
    #pragma unroll
    for (int k = 0; k < 5; k++) {
        if (etype[k] < 0) { pre[k] = make_float4(0.f, 0.f, 0.f, 0.f); continue; }
        if (etype[k] == 2) {
            pre[k] = make_float4(xg[goffs[k]], 0.f, 0.f, 0.f);
        } else {
            f4u q = *(const f4u*)(xg + goffs[k]);
            pre[k] = make_float4(q.x, q.y, q.z, q.w);
        }
    }

    float acc[2][2][2][2][4];   // [pd][ph][pw][bb][j]
    #pragma unroll
    for (int i0 = 0; i0 < 2; i0++)
    #pragma unroll
    for (int i1 = 0; i1 < 2; i1++)
    #pragma unroll
    for (int i2 = 0; i2 < 2; i2++)
    #pragma unroll
    for (int i3 = 0; i3 < 2; i3++)
    #pragma unroll
    for (int i4 = 0; i4 < 4; i4++) acc[i0][i1][i2][i3][i4] = 0.f;

    // ---- barrier-free channel loop (wave-private buffer) ----
    #pragma unroll 1
    for (int cc = 0; cc < 16; cc++) {
        // stage channel cc from pre[] into this wave's LDS buffer
        #pragma unroll
        for (int k = 0; k < 5; k++) {
            if (etype[k] < 0) continue;
            float4 c = pre[k];
            if (etype[k] == 1) c = make_float4(0.f, c.x, c.y, c.z);
            *(float4*)&ws[laddr[k]] = c;
            if (laddr2[k] >= 0) *(float4*)&ws[laddr2[k]] = c;
        }
        // prefetch channel cc+1 (hidden behind compute below)
        if (cc + 1 < 16) {
            const float* xc = xg + (size_t)(cc + 1) * XSP;
            #pragma unroll
            for (int k = 0; k < 5; k++) {
                if (etype[k] < 0) continue;
                if (etype[k] == 2) {
                    pre[k] = make_float4(xc[goffs[k]], 0.f, 0.f, 0.f);
                } else {
                    f4u q = *(const f4u*)(xc + goffs[k]);
                    pre[k] = make_float4(q.x, q.y, q.z, q.w);
                }
            }
        }

        const float* Wc = weff + (size_t)(wv * 16 + cc) * 64;  // wave-uniform
        #pragma unroll
        for (int zo = 0; zo < 3; zo++) {
            float xv[4][6];
            #pragma unroll
            for (int dy = 0; dy < 4; dy++) {
                int r = (td + zo) * 10 + 2 * th + dy;
                int sg = (r >> 1) & 3;
                int base = r * RS;
                float4 A = *(const float4*)&ws[base + 4 * ((2 * tw) ^ sg)];
                float2 B = *(const float2*)&ws[base + 4 * ((2 * tw + 1) ^ sg)];
                xv[dy][0] = A.x; xv[dy][1] = A.y; xv[dy][2] = A.z; xv[dy][3] = A.w;
                xv[dy][4] = B.x; xv[dy][5] = B.y;
            }
            #pragma unroll
            for (int pd = 0; pd < 2; pd++)
            #pragma unroll
            for (int dd = 0; dd < 2; dd++) {
                if (pd + dd != zo) continue;
                const float* Wg = Wc + (pd * 2 + dd) * 16;
                #pragma unroll
                for (int ph = 0; ph < 2; ph++)
                #pragma unroll
                for (int pw = 0; pw < 2; pw++)
                #pragma unroll
                for (int dh = 0; dh < 2; dh++)
                #pragma unroll
                for (int dw = 0; dw < 2; dw++) {
                    const float wgt = Wg[((ph * 2 + pw) * 2 + dh) * 2 + dw];
                    #pragma unroll
                    for (int bb = 0; bb < 2; bb++)
                    #pragma unroll
                    for (int j = 0; j < 4; j++)
                        acc[pd][ph][pw][bb][j] += wgt * xv[bb + ph + dh][j + pw + dw];
                }
            }
        }
    }

    // ---- in-block reduction over the 4 channel-groups (no global atomics) ----
    __syncthreads();
    float* R0 = xs;
    float* R1 = xs + 4096;
    if (wv == 1 || wv == 3) {
        float* R = (wv == 1) ? R0 : R1;
        #pragma unroll
        for (int g = 0; g < 16; g++) {
            int pd = g >> 3, ph = (g >> 2) & 1, pw = (g >> 1) & 1, bb = g & 1;
            *(float4*)&R[(g * 64 + L) * 4] =
                make_float4(acc[pd][ph][pw][bb][0], acc[pd][ph][pw][bb][1],
                            acc[pd][ph][pw][bb][2], acc[pd][ph][pw][bb][3]);
        }
    }
    __syncthreads();
    if (wv == 0 || wv == 2) {
        const float* R = (wv == 0) ? R0 : R1;
        #pragma unroll
        for (int g = 0; g < 16; g++) {
            int pd = g >> 3, ph = (g >> 2) & 1, pw = (g >> 1) & 1, bb = g & 1;
            float4 v = *(const float4*)&R[(g * 64 + L) * 4];
            acc[pd][ph][pw][bb][0] += v.x; acc[pd][ph][pw][bb][1] += v.y;
            acc[pd][ph][pw][bb][2] += v.z; acc[pd][ph][pw][bb][3] += v.w;
        }
    }
    __syncthreads();
    if (wv == 2) {
        #pragma unroll
        for (int g = 0; g < 16; g++) {
            int pd = g >> 3, ph = (g >> 2) & 1, pw = (g >> 1) & 1, bb = g & 1;
            *(float4*)&R0[(g * 64 + L) * 4] =
                make_float4(acc[pd][ph][pw][bb][0], acc[pd][ph][pw][bb][1],
                            acc[pd][ph][pw][bb][2], acc[pd][ph][pw][bb][3]);
        }
    }
    __syncthreads();
    if (wv == 0) {
        const float b0 = bias[0] * 64.0f;
        float* on = out + (size_t)n * OSP;
        #pragma unroll
        for (int g = 0; g < 16; g++) {
            int pd = g >> 3, ph = (g >> 2) & 1, pw = (g >> 1) & 1, bb = g & 1;
            float4 v = *(const float4*)&R0[(g * 64 + L) * 4];
            float t[4] = {acc[pd][ph][pw][bb][0] + v.x, acc[pd][ph][pw][bb][1] + v.y,
                          acc[pd][ph][pw][bb][2] + v.z, acc[pd][ph][pw][bb][3] + v.w};
            int od = 2 * (Bd + td) + pd;
            int oh = 2 * (Bh + 2 * th + bb) + ph;
            if (od < OUT_D && oh < OUT_D) {
                #pragma unroll
                for (int j = 0; j < 4; j++) {
                    int ow = 2 * (Bw + 4 * tw + j) + pw;
                    if (ow < OUT_D)
                        on[(od * OUT_D + oh) * OUT_D + ow] = t[j] * 64.0f + b0;
                }
            }
        }
    }
}

extern "C" void kernel_launch(void* const* d_in, const int* in_sizes, int n_in,
                              void* d_out, int out_size, void* d_ws, size_t ws_size,
                              hipStream_t stream) {
    const float* x      = (const float*)d_in[0];
    const float* weight = (const float*)d_in[1];
    const float* bias   = (const float*)d_in[2];
    float* out = (float*)d_out;
    float* weff = (float*)d_ws;        // 64*64 floats = 16 KB

    hipLaunchKernelGGL(weff_prep, dim3(1), dim3(64), 0, stream, weight, weff);

    dim3 grid(27 * BATCH, 1, 1);       // 432 blocks, n in low 4 bits
    hipLaunchKernelGGL(tconv, grid, dim3(256), 0, stream, x, weff, bias, out);
}

// Round 5
// 150.029 us; speedup vs baseline: 2.3765x; 1.0714x over previous
//
#include <hip/hip_runtime.h>

// Problem constants
#define IN_C   64
#define OUT_D  47          // (24-1)*2 - 2*1 + 3
#define XD     24
#define XSP    (XD*XD*XD)  // 13824
#define OSP    (OUT_D*OUT_D*OUT_D) // 103823
#define BATCH  16

// LDS: per-wave halo buffer. 60 rows (6 z x 10 y), row stride RS=12 floats,
// row r holds x[gz=Bd-1+r/10][gy=Bh-1+r%10][gx=Bw-1 .. Bw+10] at idx 0..11.
// 12r mod 32 cycles {0,12,24,4,16,28,8,20}: 8 consecutive rows cover all 32
// banks exactly once -> conflict-free b128 with th in the low 3 lane bits.
#define RS     12
#define NR     60
#define WBUF   (NR*RS)     // 720 floats per wave

typedef float f4u __attribute__((ext_vector_type(4), aligned(4)));

// Effective weights: weff[c*64 + (pd*2+dd)*16 + (((ph*2+pw)*2+dh)*2+dw)]
// Per dim: S(p=0,d=0)={2}, S(0,1)={0,1}, S(1,0)={1,2}, S(1,1)={0}
__global__ void weff_prep(const float* __restrict__ w, float* __restrict__ weff) {
    int c = threadIdx.x;   // 64 threads
    float wv[27];
    const float* wc = w + (size_t)c * 64 * 27;   // weight[c][0][*]
    #pragma unroll
    for (int z = 0; z < 27; z++) wv[z] = wc[z];
    const int msk[2][2] = {{4, 3}, {6, 1}};
    #pragma unroll
    for (int pd = 0; pd < 2; pd++)
    #pragma unroll
    for (int dd = 0; dd < 2; dd++)
    #pragma unroll
    for (int ph = 0; ph < 2; ph++)
    #pragma unroll
    for (int pw = 0; pw < 2; pw++)
    #pragma unroll
    for (int dh = 0; dh < 2; dh++)
    #pragma unroll
    for (int dw = 0; dw < 2; dw++) {
        float s = 0.f;
        for (int zd = 0; zd < 3; zd++) if ((msk[pd][dd] >> zd) & 1)
            for (int zh = 0; zh < 3; zh++) if ((msk[ph][dh] >> zh) & 1)
                for (int zw = 0; zw < 3; zw++) if ((msk[pw][dw] >> zw) & 1)
                    s += wv[zd * 9 + zh * 3 + zw];
        weff[c * 64 + (pd * 2 + dd) * 16 + (((ph * 2 + pw) * 2 + dh) * 2 + dw)] = s;
    }
}

// 864 blocks = 54 sp-tiles (6d x 3h x 3w in m-space) x 16 n (n in low bits).
// 256 threads = 4 waves; wave wv reduces channels [16wv,16wv+16) over the
// block's 4x8x8 m-tile in a wave-PRIVATE LDS buffer (no barriers in loop).
// Lane: th=L&7 (m-h), tw=(L>>3)&1 (4 m-w), td=L>>4 (m-d). 32 accs/thread.
// In-block LDS tree-reduction, plain stores (no global atomics).
__global__ __launch_bounds__(256, 4) void tconv(const float* __restrict__ x,
                                                const float* __restrict__ weff,
                                                const float* __restrict__ bias,
                                                float* __restrict__ out) {
    __shared__ float xs[4096];      // 16 KB: 4x720 staging, overlaid 2x2048 reduce
    const int b = blockIdx.x;
    const int n = b & 15;
    const int sp = b >> 4;          // 0..53
    const int tz = sp / 9;
    const int r9 = sp - tz * 9;
    const int ty = r9 / 3;
    const int tx = r9 - ty * 3;
    const int Bd = tz * 4, Bh = ty * 8, Bw = tx * 8;

    const int tid = threadIdx.x;
    const int wv = tid >> 6;
    const int L  = tid & 63;
    const int th = L & 7;
    const int tw = (L >> 3) & 1;
    const int td = L >> 4;          // 0..3

    float* ws = xs + wv * WBUF;

    // one-time zero fill (invalid halo rows must read as 0)
    #pragma unroll
    for (int i = 0; i < 16; i++) xs[tid + 256 * i] = 0.f;
    __syncthreads();

    // ---- channel-invariant staging descriptors: 3 units/lane ----
    // unit e = u*60 + r (u = x-quad 0..2, r = row): 8-lane phases get
    // consecutive r -> perfect bank spread on the b128 writes.
    int gofs[3], lad[3], et[3];     // et: -1 skip, 0 full, 1 shift-left, 2 scalar
    #pragma unroll
    for (int k = 0; k < 3; k++) {
        int e = k * 64 + L;
        int u = e / 60;
        int r = e - u * 60;
        int z = r / 10;
        int y = r - z * 10;
        int gz = Bd - 1 + z, gy = Bh - 1 + y;
        bool rv = (e < 180) && ((unsigned)gz < (unsigned)XD) &&
                  ((unsigned)gy < (unsigned)XD);
        int gxs = Bw - 1 + 4 * u;
        int t;
        if (!rv) t = -1;
        else if (gxs < 0) t = 1;          // Bw=0,u=0: gx -1..2
        else if (gxs + 3 > XD - 1) t = 2; // Bw=16,u=2: gx 23..26
        else t = 0;
        et[k] = t;
        gofs[k] = (gz * XD + gy) * XD + (gxs < 0 ? 0 : gxs);
        lad[k] = r * RS + 4 * u;
    }

    const float* xg = x + ((size_t)n * IN_C + wv * 16) * XSP;

    // ---- prologue prefetch: channel 0 ----
    float4 pre[3];
    #pragma unroll
    for (int k = 0; k < 3; k++) {
        if (et[k] < 0) pre[k] = make_float4(0.f, 0.f, 0.f, 0.f);
        else if (et[k] == 2) pre[k] = make_float4(xg[gofs[k]], 0.f, 0.f, 0.f);
        else { f4u q = *(const f4u*)(xg + gofs[k]);
               pre[k] = make_float4(q.x, q.y, q.z, q.w); }
    }

    float acc[2][2][2][4];          // [pd][ph][pw][j]
    #pragma unroll
    for (int i0 = 0; i0 < 2; i0++)
    #pragma unroll
    for (int i1 = 0; i1 < 2; i1++)
    #pragma unroll
    for (int i2 = 0; i2 < 2; i2++)
    #pragma unroll
    for (int i3 = 0; i3 < 4; i3++) acc[i0][i1][i2][i3] = 0.f;

    // ---- barrier-free channel loop (wave-private buffer) ----
    #pragma unroll 1
    for (int cc = 0; cc < 16; cc++) {
        #pragma unroll
        for (int k = 0; k < 3; k++) {
            if (et[k] >= 0) {
                float4 c = pre[k];
                if (et[k] == 1) c = make_float4(0.f, c.x, c.y, c.z);
                *(float4*)&ws[lad[k]] = c;
            }
        }
        if (cc + 1 < 16) {
            const float* xc = xg + (size_t)(cc + 1) * XSP;
            #pragma unroll
            for (int k = 0; k < 3; k++) {
                if (et[k] < 0) continue;
                if (et[k] == 2) pre[k] = make_float4(xc[gofs[k]], 0.f, 0.f, 0.f);
                else { f4u q = *(const f4u*)(xc + gofs[k]);
                       pre[k] = make_float4(q.x, q.y, q.z, q.w); }
            }
        }

        const float* Wc = weff + (size_t)(wv * 16 + cc) * 64;  // wave-uniform
        #pragma unroll
        for (int zo = 0; zo < 3; zo++) {
            float xv[3][6];
            #pragma unroll
            for (int dy = 0; dy < 3; dy++) {
                int base = ((td + zo) * 10 + th + dy) * RS + 4 * tw;
                float4 A = *(const float4*)&ws[base];
                float2 Bv = *(const float2*)&ws[base + 4];
                xv[dy][0] = A.x;  xv[dy][1] = A.y;  xv[dy][2] = A.z;
                xv[dy][3] = A.w;  xv[dy][4] = Bv.x; xv[dy][5] = Bv.y;
            }
            #pragma unroll
            for (int pd = 0; pd < 2; pd++)
            #pragma unroll
            for (int dd = 0; dd < 2; dd++) {
                if (pd + dd != zo) continue;
                const float* Wg = Wc + (pd * 2 + dd) * 16;
                #pragma unroll
                for (int ph = 0; ph < 2; ph++)
                #pragma unroll
                for (int pw = 0; pw < 2; pw++)
                #pragma unroll
                for (int dh = 0; dh < 2; dh++)
                #pragma unroll
                for (int dw = 0; dw < 2; dw++) {
                    const float wgt = Wg[((ph * 2 + pw) * 2 + dh) * 2 + dw];
                    #pragma unroll
                    for (int j = 0; j < 4; j++)
                        acc[pd][ph][pw][j] += wgt * xv[ph + dh][j + pw + dw];
                }
            }
        }
    }

    // ---- in-block tree reduction over the 4 channel-groups ----
    __syncthreads();
    float* R0 = xs;
    float* R1 = xs + 2048;
    if (wv == 1 || wv == 3) {
        float* R = (wv == 1) ? R0 : R1;
        #pragma unroll
        for (int g = 0; g < 8; g++) {
            int pd = g >> 2, ph = (g >> 1) & 1, pw = g & 1;
            *(float4*)&R[(g * 64 + L) * 4] =
                make_float4(acc[pd][ph][pw][0], acc[pd][ph][pw][1],
                            acc[pd][ph][pw][2], acc[pd][ph][pw][3]);
        }
    }
    __syncthreads();
    if (wv == 0 || wv == 2) {
        const float* R = (wv == 0) ? R0 : R1;
        #pragma unroll
        for (int g = 0; g < 8; g++) {
            int pd = g >> 2, ph = (g >> 1) & 1, pw = g & 1;
            float4 v = *(const float4*)&R[(g * 64 + L) * 4];
            acc[pd][ph][pw][0] += v.x; acc[pd][ph][pw][1] += v.y;
            acc[pd][ph][pw][2] += v.z; acc[pd][ph][pw][3] += v.w;
        }
    }
    __syncthreads();
    if (wv == 2) {
        #pragma unroll
        for (int g = 0; g < 8; g++) {
            int pd = g >> 2, ph = (g >> 1) & 1, pw = g & 1;
            *(float4*)&R0[(g * 64 + L) * 4] =
                make_float4(acc[pd][ph][pw][0], acc[pd][ph][pw][1],
                            acc[pd][ph][pw][2], acc[pd][ph][pw][3]);
        }
    }
    __syncthreads();
    if (wv == 0) {
        const float b0 = bias[0] * 64.0f;
        float* on = out + (size_t)n * OSP;
        #pragma unroll
        for (int g = 0; g < 8; g++) {
            int pd = g >> 2, ph = (g >> 1) & 1, pw = g & 1;
            float4 v = *(const float4*)&R0[(g * 64 + L) * 4];
            float t[4] = {acc[pd][ph][pw][0] + v.x, acc[pd][ph][pw][1] + v.y,
                          acc[pd][ph][pw][2] + v.z, acc[pd][ph][pw][3] + v.w};
            int od = 2 * (Bd + td) + pd;
            int oh = 2 * (Bh + th) + ph;
            if (od < OUT_D && oh < OUT_D) {
                #pragma unroll
                for (int j = 0; j < 4; j++) {
                    int ow = 2 * (Bw + 4 * tw + j) + pw;
                    if (ow < OUT_D)
                        on[(od * OUT_D + oh) * OUT_D + ow] = t[j] * 64.0f + b0;
                }
            }
        }
    }
}

extern "C" void kernel_launch(void* const* d_in, const int* in_sizes, int n_in,
                              void* d_out, int out_size, void* d_ws, size_t ws_size,
                              hipStream_t stream) {
    const float* x      = (const float*)d_in[0];
    const float* weight = (const float*)d_in[1];
    const float* bias   = (const float*)d_in[2];
    float* out = (float*)d_out;
    float* weff = (float*)d_ws;        // 64*64 floats = 16 KB

    hipLaunchKernelGGL(weff_prep, dim3(1), dim3(64), 0, stream, weight, weff);

    dim3 grid(54 * BATCH, 1, 1);       // 864 blocks, n in low 4 bits
    hipLaunchKernelGGL(tconv, grid, dim3(256), 0, stream, x, weff, bias, out);
}